// Round 1
// 1318.681 us; speedup vs baseline: 1.2355x; 1.2355x over previous
//
#include <hip/hip_runtime.h>
#include <cstdint>
#include <cstddef>

// Problem constants: E experts, N tokens/expert, D dim, H hidden
#define NE 16
#define NTOK 2048
#define DDIM 1024
#define HDIM 4096

typedef unsigned short u16;
typedef __bf16 bf16x8 __attribute__((ext_vector_type(8)));
typedef float f32x4 __attribute__((ext_vector_type(4)));
typedef unsigned int u32x4 __attribute__((ext_vector_type(4)));

typedef __attribute__((address_space(1))) const void as1_cvoid;
typedef __attribute__((address_space(3))) void as3_void;

// async global->LDS, 16B per lane. LDS dest wave-uniform base; HW scatters
// lane i to base + i*16. Global source is per-lane (swizzle goes there).
__device__ __forceinline__ void load_lds16(const void* g, void* l) {
    __builtin_amdgcn_global_load_lds((as1_cvoid*)g, (as3_void*)l, 16, 0, 0);
}

// fp32 -> bf16 round-to-nearest-even
__device__ __forceinline__ u16 f2bf(float f) {
    uint32_t x = __float_as_uint(f);
    x += 0x7FFFu + ((x >> 16) & 1u);
    return (u16)(x >> 16);
}

// raw barrier (NO compiler-inserted vmcnt(0) drain, unlike __syncthreads)
#define S_BARRIER() asm volatile("s_barrier" ::: "memory")
// counted VMEM wait (the T4 lever: never drain to 0 mid-loop)
#define WAIT_VM(N) asm volatile("s_waitcnt vmcnt(" #N ")" ::: "memory")
// LDS wait + sched fence: hipcc may hoist register-only MFMA past the asm
// wait (rule #18) -> sched_barrier(0) is mandatory here.
#define WAIT_LGKM0()                                        \
    do {                                                    \
        asm volatile("s_waitcnt lgkmcnt(0)" ::: "memory");  \
        __builtin_amdgcn_sched_barrier(0);                  \
    } while (0)

#define MFMA16(a, b, c) __builtin_amdgcn_mfma_f32_16x16x32_bf16((a), (b), (c), 0, 0, 0)

// opaque LDS read: compiler must not see the LDS dependency, else it inserts
// vmcnt(0) before it (LDS-DMA hazard tracking) and kills the pipeline.
__device__ __forceinline__ bf16x8 lds_read_b128(uint32_t byte_off) {
    u32x4 r;
    asm volatile("ds_read_b128 %0, %1" : "=v"(r) : "v"(byte_off));
    return __builtin_bit_cast(bf16x8, r);
}

// ---- elementwise cast x: fp32 -> bf16, 4 elems/thread ----
__global__ void cvt_x_kernel(const float* __restrict__ in, u16* __restrict__ out, size_t n4) {
    size_t i = (size_t)blockIdx.x * blockDim.x + threadIdx.x;
    if (i >= n4) return;
    float4 v = ((const float4*)in)[i];
    uint32_t lo = (uint32_t)f2bf(v.x) | ((uint32_t)f2bf(v.y) << 16);
    uint32_t hi = (uint32_t)f2bf(v.z) | ((uint32_t)f2bf(v.w) << 16);
    ((uint2*)out)[i] = make_uint2(lo, hi);
}

// ---- per-expert transpose + cast: in [E][R][C] fp32 -> out [E][C][R] bf16 ----
__global__ void transpose_cvt_kernel(const float* __restrict__ in, u16* __restrict__ out,
                                     int R, int C) {
    __shared__ u16 tile[32][33];
    int e = blockIdx.z;
    const float* pin = in + (size_t)e * R * C;
    u16* pout = out + (size_t)e * R * C;
    int c0 = blockIdx.x * 32, r0 = blockIdx.y * 32;
#pragma unroll
    for (int i = 0; i < 4; ++i) {
        int r = r0 + threadIdx.y + i * 8;
        tile[threadIdx.y + i * 8][threadIdx.x] = f2bf(pin[(size_t)r * C + c0 + threadIdx.x]);
    }
    __syncthreads();
#pragma unroll
    for (int i = 0; i < 4; ++i) {
        int c = c0 + threadIdx.y + i * 8;
        pout[(size_t)c * R + r0 + threadIdx.x] = tile[threadIdx.x][threadIdx.y + i * 8];
    }
}

// ============================================================================
// 256x256-tile, BK=64, 8-wave (2M x 4N), 8-phase counted-vmcnt GEMM.
//   C[e] = A[e] (MxK) * Bt[e]^T   (Bt is [Nout][K], both bf16)
//
// LDS (128 KiB): A planes [buf:2][ks:2][256 rows][32 u16]  (16 KiB each)
//                B planes same, at +64 KiB.
// Per K-tile (64 wide) = 4 planes {A-ks0, B-ks0, A-ks1, B-ks1}; each plane
// staged by 2 global_load_lds per wave. Compute = 4 phases/K-tile
// (ks x n-half), 16 MFMA each. Plane staged in phase p is consumed 4 phases
// later; vmcnt(4) at the end of P0b/P1b publishes exactly the 2 planes the
// next 2 phases need. Never vmcnt(0) in steady state.
//
// Swizzle (T2): LDS row = 64 B = 4 chunks of 16 B. Data chunk c of row r is
// stored at slot c ^ ((r>>1)&3). Staging keeps LDS dest linear and applies
// the inverse permutation on the per-lane GLOBAL address (rule 21):
// chunk = (lane&3) ^ ((lane>>3)&3). A fragment read (16 rows x 4 chunks)
// then touches all 8 bank-granules with 2 lanes each -> conflict-free.
// ============================================================================
template <bool GELU>
__global__ void __launch_bounds__(512, 2)
gemm256_kernel(const u16* __restrict__ A, const u16* __restrict__ Bt,
               const float* __restrict__ bias, void* __restrict__ Cout,
               int M, int K, int Nout) {
    __shared__ u16 ldsU[65536];  // 128 KiB

    const int e = blockIdx.z;
    const u16* Ae = A + (size_t)e * M * K;
    const u16* Be = Bt + (size_t)e * Nout * K;

    const int tid = threadIdx.x;
    const int wave = tid >> 6, lane = tid & 63;
    const int wr = wave >> 2;   // 0..1 : M side (128 rows each)
    const int wc = wave & 3;    // 0..3 : N side (64 cols each)

    const int m_blk = blockIdx.y * 256, n_blk = blockIdx.x * 256;

    // ---- staging addressing (per-lane global, linear LDS dest) ----
    // wave w stages plane rows [w*32, w*32+32): issue j covers 16 rows.
    const int schunk = (lane & 3) ^ ((lane >> 3) & 3);  // inverse swizzle
    const u16* aG = Ae + (size_t)(m_blk + wave * 32 + (lane >> 2)) * K + schunk * 8;
    const u16* bG = Be + (size_t)(n_blk + wave * 32 + (lane >> 2)) * K + schunk * 8;
    const size_t rowJ = (size_t)16 * K;  // +16 rows for issue j=1

    // ---- fragment read addressing (bytes, swizzled) ----
    const int p = lane & 15, q = lane >> 4;
    const int sq = q ^ ((p >> 1) & 3);  // (row>>1)&3 == (p>>1)&3 (row%16==p)
    const uint32_t ardB = (uint32_t)((wr * 128 + p) * 64 + sq * 16);
    const uint32_t brdB = (uint32_t)((wc * 64 + p) * 64 + sq * 16);

    f32x4 acc[8][4];
#pragma unroll
    for (int i = 0; i < 8; ++i)
#pragma unroll
        for (int j = 0; j < 4; ++j) acc[i][j] = (f32x4){0.f, 0.f, 0.f, 0.f};

    const int NT = K >> 6;

    // ---- prologue: stage tile 0 (order A0,B0,A1,B1 = vmcnt count basis) ----
    {
        u16* dA0 = ldsU + wave * 1024;            // (buf0, ks0) A
        u16* dA1 = ldsU + 8192 + wave * 1024;     // (buf0, ks1) A
        u16* dB0 = ldsU + 32768 + wave * 1024;    // (buf0, ks0) B
        u16* dB1 = ldsU + 40960 + wave * 1024;    // (buf0, ks1) B
        load_lds16(aG, dA0);       load_lds16(aG + rowJ, dA0 + 512);
        load_lds16(bG, dB0);       load_lds16(bG + rowJ, dB0 + 512);
        load_lds16(aG + 32, dA1);  load_lds16(aG + 32 + rowJ, dA1 + 512);
        load_lds16(bG + 32, dB1);  load_lds16(bG + 32 + rowJ, dB1 + 512);
    }
    WAIT_VM(4);  // A-ks0(0), B-ks0(0) landed (per wave); barrier publishes
    S_BARRIER();

    for (int t = 0; t < NT; ++t) {
        const bool hn = (t + 1 < NT);
        const uint32_t buf = (uint32_t)(t & 1), nb = buf ^ 1u;
        // current-tile plane byte bases
        const uint32_t aP0 = (buf * 2 + 0) * 16384u;
        const uint32_t aP1 = (buf * 2 + 1) * 16384u;
        const uint32_t bP0 = 65536u + (buf * 2 + 0) * 16384u;
        const uint32_t bP1 = 65536u + (buf * 2 + 1) * 16384u;
        // next-tile stage dests (u16*, wave-uniform)
        u16* nA0 = ldsU + (nb * 2 + 0) * 8192 + wave * 1024;
        u16* nA1 = ldsU + (nb * 2 + 1) * 8192 + wave * 1024;
        u16* nB0 = ldsU + 32768 + (nb * 2 + 0) * 8192 + wave * 1024;
        u16* nB1 = ldsU + 32768 + (nb * 2 + 1) * 8192 + wave * 1024;
        const u16* gA = aG + (size_t)(t + 1) * 64;
        const u16* gB = bG + (size_t)(t + 1) * 64;

        bf16x8 af[8], bf0, bf1;

        // -------- P0a: ks0, n-frags 0,1 --------
#pragma unroll
        for (int i = 0; i < 8; ++i) af[i] = lds_read_b128(aP0 + ardB + (uint32_t)i * 1024u);
        bf0 = lds_read_b128(bP0 + brdB);
        bf1 = lds_read_b128(bP0 + brdB + 1024u);
        if (hn) { load_lds16(gA, nA0); load_lds16(gA + rowJ, nA0 + 512); }
        S_BARRIER();
        WAIT_LGKM0();
        __builtin_amdgcn_s_setprio(1);
#pragma unroll
        for (int i = 0; i < 8; ++i) {
            acc[i][0] = MFMA16(af[i], bf0, acc[i][0]);
            acc[i][1] = MFMA16(af[i], bf1, acc[i][1]);
        }
        __builtin_amdgcn_s_setprio(0);
        S_BARRIER();

        // -------- P0b: ks0, n-frags 2,3 --------
        bf0 = lds_read_b128(bP0 + brdB + 2048u);
        bf1 = lds_read_b128(bP0 + brdB + 3072u);
        if (hn) { load_lds16(gB, nB0); load_lds16(gB + rowJ, nB0 + 512); }
        S_BARRIER();
        WAIT_LGKM0();
        __builtin_amdgcn_s_setprio(1);
#pragma unroll
        for (int i = 0; i < 8; ++i) {
            acc[i][2] = MFMA16(af[i], bf0, acc[i][2]);
            acc[i][3] = MFMA16(af[i], bf1, acc[i][3]);
        }
        __builtin_amdgcn_s_setprio(0);
        // publish A-ks1(t), B-ks1(t): outstanding = {A1(t),B1(t),A0(t+1),B0(t+1)}
        if (hn) { WAIT_VM(4); } else { WAIT_VM(0); }
        S_BARRIER();

        // -------- P1a: ks1, n-frags 0,1 --------
#pragma unroll
        for (int i = 0; i < 8; ++i) af[i] = lds_read_b128(aP1 + ardB + (uint32_t)i * 1024u);
        bf0 = lds_read_b128(bP1 + brdB);
        bf1 = lds_read_b128(bP1 + brdB + 1024u);
        if (hn) { load_lds16(gA + 32, nA1); load_lds16(gA + 32 + rowJ, nA1 + 512); }
        S_BARRIER();
        WAIT_LGKM0();
        __builtin_amdgcn_s_setprio(1);
#pragma unroll
        for (int i = 0; i < 8; ++i) {
            acc[i][0] = MFMA16(af[i], bf0, acc[i][0]);
            acc[i][1] = MFMA16(af[i], bf1, acc[i][1]);
        }
        __builtin_amdgcn_s_setprio(0);
        S_BARRIER();

        // -------- P1b: ks1, n-frags 2,3 --------
        bf0 = lds_read_b128(bP1 + brdB + 2048u);
        bf1 = lds_read_b128(bP1 + brdB + 3072u);
        if (hn) { load_lds16(gB + 32, nB1); load_lds16(gB + 32 + rowJ, nB1 + 512); }
        S_BARRIER();
        WAIT_LGKM0();
        __builtin_amdgcn_s_setprio(1);
#pragma unroll
        for (int i = 0; i < 8; ++i) {
            acc[i][2] = MFMA16(af[i], bf0, acc[i][2]);
            acc[i][3] = MFMA16(af[i], bf1, acc[i][3]);
        }
        __builtin_amdgcn_s_setprio(0);
        // publish A-ks0(t+1), B-ks0(t+1) for next tile's P0a/P0b
        if (hn) { WAIT_VM(4); }
        S_BARRIER();
    }

    // ---- epilogue: C/D layout col = lane&15, row = (lane>>4)*4 + r ----
    const int rb = (lane >> 4) * 4;
    const int cb = lane & 15;
    const size_t eoff = (size_t)e * M * Nout;
#pragma unroll
    for (int i = 0; i < 8; ++i) {
#pragma unroll
        for (int j = 0; j < 4; ++j) {
            const int col = n_blk + wc * 64 + j * 16 + cb;
            const float bv = bias[col];
#pragma unroll
            for (int r = 0; r < 4; ++r) {
                const int row = m_blk + wr * 128 + i * 16 + rb + r;
                float v = acc[i][j][r] + bv;
                if (GELU) {
                    float g = 0.5f * v * (1.0f + erff(v * 0.70710678118654752f));
                    ((u16*)Cout)[eoff + (size_t)row * Nout + col] = f2bf(g);
                } else {
                    ((float*)Cout)[eoff + (size_t)row * Nout + col] = v;
                }
            }
        }
    }
}

extern "C" void kernel_launch(void* const* d_in, const int* in_sizes, int n_in,
                              void* d_out, int out_size, void* d_ws, size_t ws_size,
                              hipStream_t stream) {
    (void)in_sizes; (void)n_in; (void)out_size; (void)ws_size;
    const float* x  = (const float*)d_in[0];
    const float* w1 = (const float*)d_in[1];
    const float* w2 = (const float*)d_in[2];
    const float* b1 = (const float*)d_in[3];
    const float* b2 = (const float*)d_in[4];
    float* out = (float*)d_out;

    // workspace layout (bytes):
    //   xb  : E*N*D*2  =  64 MiB   (x in bf16)
    //   w1t : E*H*D*2  = 128 MiB   (w1^T per expert, bf16, [e][h][d])
    //   w2t : E*D*H*2  = 128 MiB   (w2^T per expert, bf16, [e][d][h])
    //   hid : E*N*H*2  = 256 MiB   (gelu(x@w1+b1) in bf16)
    char* ws = (char*)d_ws;
    u16* xb  = (u16*)ws;
    u16* w1t = (u16*)(ws + (size_t)NE * NTOK * DDIM * 2);
    u16* w2t = (u16*)(ws + (size_t)NE * NTOK * DDIM * 2 + (size_t)NE * HDIM * DDIM * 2);
    u16* hid = (u16*)(ws + (size_t)NE * NTOK * DDIM * 2 + (size_t)2 * NE * HDIM * DDIM * 2);

    // 1) casts / transposes
    {
        size_t n4 = (size_t)NE * NTOK * DDIM / 4;
        cvt_x_kernel<<<(unsigned)((n4 + 255) / 256), 256, 0, stream>>>(x, xb, n4);
    }
    transpose_cvt_kernel<<<dim3(HDIM / 32, DDIM / 32, NE), dim3(32, 8), 0, stream>>>(w1, w1t, DDIM, HDIM);
    transpose_cvt_kernel<<<dim3(DDIM / 32, HDIM / 32, NE), dim3(32, 8), 0, stream>>>(w2, w2t, HDIM, DDIM);

    // 2) hidden = gelu(x @ w1 + b1), bf16 out
    gemm256_kernel<true><<<dim3(HDIM / 256, NTOK / 256, NE), 512, 0, stream>>>(
        xb, w1t, b1, (void*)hid, NTOK, DDIM, HDIM);

    // 3) out = hidden @ w2 + b2, fp32 out
    gemm256_kernel<false><<<dim3(DDIM / 256, NTOK / 256, NE), 512, 0, stream>>>(
        hid, w2t, b2, (void*)out, NTOK, HDIM, DDIM);
}